// Round 2
// baseline (803.615 us; speedup 1.0000x reference)
//
#include <hip/hip_runtime.h>

// Fused: out = swish(swish(groupnorm(x@W + b)) * mw)
// M=65536, K=1024, N=1024, G=32 (group width 32 channels)
//
// Kernel 1: W fp32 [K][N] -> Wt bf16 [N][K] (transposed, for contiguous-K tiles)
// Kernel 2: 128x128x32 bf16-MFMA GEMM, GroupNorm+swish epilogue fused in-register.

typedef __attribute__((ext_vector_type(8))) short short8;
typedef __attribute__((ext_vector_type(4))) float floatx4;

#define K_DIM 1024
#define N_DIM 1024
#define BM 128
#define BN 128
#define BK 32
#define SA 40   // padded As row stride in bf16 elems (80 B -> conflict-free ds_read_b128)

__device__ __forceinline__ unsigned short f2bf(float f) {
    // round-to-nearest-even fp32 -> bf16
    unsigned int u = __float_as_uint(f);
    u += 0x7FFFu + ((u >> 16) & 1u);
    return (unsigned short)(u >> 16);
}

__device__ __forceinline__ short8 pack8(floatx4 a, floatx4 b) {
    short8 r;
    r[0] = (short)f2bf(a[0]); r[1] = (short)f2bf(a[1]);
    r[2] = (short)f2bf(a[2]); r[3] = (short)f2bf(a[3]);
    r[4] = (short)f2bf(b[0]); r[5] = (short)f2bf(b[1]);
    r[6] = (short)f2bf(b[2]); r[7] = (short)f2bf(b[3]);
    return r;
}

// ---- Kernel 1: transpose + convert W -> Wt (bf16, [N][K]) ----
__global__ __launch_bounds__(256) void prep_w_kernel(const float* __restrict__ W,
                                                     unsigned short* __restrict__ Wt) {
    __shared__ float s[32][33];
    const int tx = threadIdx.x & 31;
    const int ty = threadIdx.x >> 5;        // 0..7
    const int kt = (blockIdx.x & 31) << 5;  // k tile origin
    const int nt = (blockIdx.x >> 5) << 5;  // n tile origin
    #pragma unroll
    for (int i = 0; i < 4; ++i)
        s[ty + i * 8][tx] = W[(size_t)(kt + ty + i * 8) * N_DIM + nt + tx];
    __syncthreads();
    #pragma unroll
    for (int i = 0; i < 4; ++i)
        Wt[(size_t)(nt + ty + i * 8) * K_DIM + kt + tx] = f2bf(s[tx][ty + i * 8]);
}

// ---- Kernel 2: fused GEMM + bias + GroupNorm + swish*mw*swish ----
__global__ __launch_bounds__(256) void fused_kernel(const float* __restrict__ x,
                                                    const unsigned short* __restrict__ Wt,
                                                    const float* __restrict__ bias,
                                                    const float* __restrict__ mulw,
                                                    float* __restrict__ out) {
    __shared__ unsigned short As[BM * SA];  // 10240 B, padded
    __shared__ unsigned short Bs[BN * BK];  // 8192 B, unpadded (global_load_lds layout)

    const int tid  = threadIdx.x;
    const int lane = tid & 63;
    const int wid  = tid >> 6;     // 4 waves
    const int wm   = wid >> 1;     // 2x2 wave grid
    const int wn   = wid & 1;
    const int q    = lane >> 4;    // quad (k-phase for A/B frags; row-phase for C)
    const int ln   = lane & 15;

    const int bCol = blockIdx.x & 7;    // fastest -> 8 blocks share one x row-panel
    const int bRow = blockIdx.x >> 3;
    const int m0 = bRow * BM;
    const int n0 = bCol * BN;

    floatx4 acc[4][4];
    #pragma unroll
    for (int i = 0; i < 4; ++i)
        #pragma unroll
        for (int j = 0; j < 4; ++j)
            acc[i][j] = (floatx4){0.f, 0.f, 0.f, 0.f};

    // A staging: thread t handles As row t/2, 16 contiguous k at col (t&1)*16
    const int arow = tid >> 1;
    const int acol = (tid & 1) << 4;
    const float* xptr = x + (size_t)(m0 + arow) * K_DIM + acol;
    unsigned short* aw = As + arow * SA + acol;

    // B staging via global_load_lds: per wave 2 issues of 16 rows x 32 k
    const int bnr = (lane >> 2);          // row-within-16 (4 lanes/row)
    const int bkc = (lane & 3) << 3;      // 8-elem k chunk
    const unsigned short* wtp = Wt + (size_t)(n0 + wid * 32 + bnr) * K_DIM + bkc;

    // fragment read bases
    const unsigned short* ard = As + (wm * 64 + ln) * SA + q * 8;
    const unsigned short* brd = Bs + (wn * 64 + ln) * BK + q * 8;

    for (int k0 = 0; k0 < K_DIM; k0 += BK) {
        __syncthreads();
        // async B tiles -> LDS (lds dest is wave-uniform base + lane*16)
        #pragma unroll
        for (int j = 0; j < 2; ++j) {
            const unsigned short* gp = wtp + (size_t)j * 16 * K_DIM + k0;
            unsigned short* lp = Bs + (wid * 2 + j) * 512;
            __builtin_amdgcn_global_load_lds(
                (const __attribute__((address_space(1))) unsigned int*)gp,
                (__attribute__((address_space(3))) unsigned int*)lp,
                16, 0, 0);
        }
        // A tile: fp32 load -> bf16 pack -> LDS
        floatx4 f0 = *(const floatx4*)(xptr + k0);
        floatx4 f1 = *(const floatx4*)(xptr + k0 + 4);
        floatx4 f2 = *(const floatx4*)(xptr + k0 + 8);
        floatx4 f3 = *(const floatx4*)(xptr + k0 + 12);
        *(short8*)aw       = pack8(f0, f1);
        *(short8*)(aw + 8) = pack8(f2, f3);
        __syncthreads();

        short8 af[4], bfv[4];
        #pragma unroll
        for (int im = 0; im < 4; ++im)
            af[im] = *(const short8*)(ard + im * 16 * SA);
        #pragma unroll
        for (int in = 0; in < 4; ++in)
            bfv[in] = *(const short8*)(brd + in * 16 * BK);
        #pragma unroll
        for (int im = 0; im < 4; ++im)
            #pragma unroll
            for (int in = 0; in < 4; ++in)
                acc[im][in] = __builtin_amdgcn_mfma_f32_16x16x32_bf16(
                    af[im], bfv[in], acc[im][in], 0, 0, 0);
    }

    // ---- epilogue: bias + GroupNorm(32-wide groups) + swish * mw + swish ----
    // C/D layout: col = ln, row = q*4 + r. Wave covers cols wn*64 + in*16 + ln.
    float bv[4], wv[4];
    #pragma unroll
    for (int in = 0; in < 4; ++in) {
        int col = n0 + wn * 64 + in * 16 + ln;
        bv[in] = bias[col];
        wv[in] = mulw[col];
    }
    #pragma unroll
    for (int im = 0; im < 4; ++im)
        #pragma unroll
        for (int in = 0; in < 4; ++in)
            #pragma unroll
            for (int r = 0; r < 4; ++r)
                acc[im][in][r] += bv[in];

    const float inv32 = 1.0f / 32.0f;
    #pragma unroll
    for (int im = 0; im < 4; ++im) {
        const int rowb = m0 + wm * 64 + im * 16 + q * 4;
        #pragma unroll
        for (int p = 0; p < 2; ++p) {   // group p covers tiles in=2p, 2p+1 (32 cols)
            const int i0 = 2 * p, i1 = 2 * p + 1;
            float mean[4], rstd[4];
            #pragma unroll
            for (int r = 0; r < 4; ++r) {
                float y0 = acc[im][i0][r], y1 = acc[im][i1][r];
                float s1 = y0 + y1;
                float s2 = y0 * y0 + y1 * y1;
                #pragma unroll
                for (int d = 1; d < 16; d <<= 1) {   // butterfly within 16-lane quad
                    s1 += __shfl_xor(s1, d, 64);
                    s2 += __shfl_xor(s2, d, 64);
                }
                float mn = s1 * inv32;
                float var = s2 * inv32 - mn * mn;
                mean[r] = mn;
                rstd[r] = rsqrtf(var + 1e-5f);
            }
            #pragma unroll
            for (int ii = i0; ii <= i1; ++ii) {
                const int col = n0 + wn * 64 + ii * 16 + ln;
                const float w = wv[ii];
                #pragma unroll
                for (int r = 0; r < 4; ++r) {
                    float y   = acc[im][ii][r];
                    float nrm = (y - mean[r]) * rstd[r];
                    float s   = nrm / (1.0f + __expf(-nrm));
                    float m2  = s * w;
                    float o   = m2 / (1.0f + __expf(-m2));
                    out[(size_t)(rowb + r) * N_DIM + col] = o;
                }
            }
        }
    }
}

extern "C" void kernel_launch(void* const* d_in, const int* in_sizes, int n_in,
                              void* d_out, int out_size, void* d_ws, size_t ws_size,
                              hipStream_t stream) {
    const float* x  = (const float*)d_in[0];
    const float* W  = (const float*)d_in[1];
    const float* b  = (const float*)d_in[2];
    const float* mw = (const float*)d_in[3];
    float* out = (float*)d_out;
    unsigned short* Wt = (unsigned short*)d_ws;  // 1024*1024 bf16 = 2 MB

    prep_w_kernel<<<1024, 256, 0, stream>>>(W, Wt);

    const int M = in_sizes[0] / K_DIM;            // 65536
    const int grid = (M / BM) * (N_DIM / BN);     // 512 * 8 = 4096
    fused_kernel<<<grid, 256, 0, stream>>>(x, Wt, b, mw, out);
}